// Round 8
// baseline (155.278 us; speedup 1.0000x reference)
//
#include <hip/hip_runtime.h>

#define DIM  128
#define HID  32
#define KTOT 384          // 3*DIM
#define TPW  16           // edges per wave-tile

typedef __attribute__((ext_vector_type(4))) float f32x4;
typedef __attribute__((ext_vector_type(2))) float f32x2;

// fp8 e4m3 (OCP on gfx950) pack/unpack via HW converts
static __device__ __forceinline__ unsigned pk4_fp8(float a, float b, float c, float d) {
    unsigned r = __builtin_amdgcn_cvt_pk_fp8_f32(a, b, 0u, false);
    return __builtin_amdgcn_cvt_pk_fp8_f32(c, d, r, true);
}

// elementwise product of two 8-byte fp8 vectors, result fp8
static __device__ __forceinline__ long prod_fp8(long a, long b) {
    unsigned alo = (unsigned)(unsigned long)a, ahi = (unsigned)((unsigned long)a >> 32);
    unsigned blo = (unsigned)(unsigned long)b, bhi = (unsigned)((unsigned long)b >> 32);
    f32x2 a0 = __builtin_amdgcn_cvt_pk_f32_fp8(alo, false);
    f32x2 a1 = __builtin_amdgcn_cvt_pk_f32_fp8(alo, true);
    f32x2 a2 = __builtin_amdgcn_cvt_pk_f32_fp8(ahi, false);
    f32x2 a3 = __builtin_amdgcn_cvt_pk_f32_fp8(ahi, true);
    f32x2 b0 = __builtin_amdgcn_cvt_pk_f32_fp8(blo, false);
    f32x2 b1 = __builtin_amdgcn_cvt_pk_f32_fp8(blo, true);
    f32x2 b2 = __builtin_amdgcn_cvt_pk_f32_fp8(bhi, false);
    f32x2 b3 = __builtin_amdgcn_cvt_pk_f32_fp8(bhi, true);
    f32x2 p0 = a0 * b0, p1 = a1 * b1, p2 = a2 * b2, p3 = a3 * b3;
    unsigned plo = __builtin_amdgcn_cvt_pk_fp8_f32(p0.x, p0.y, 0u, false);
    plo = __builtin_amdgcn_cvt_pk_fp8_f32(p1.x, p1.y, plo, true);
    unsigned phi = __builtin_amdgcn_cvt_pk_fp8_f32(p2.x, p2.y, 0u, false);
    phi = __builtin_amdgcn_cvt_pk_fp8_f32(p3.x, p3.y, phi, true);
    return (long)(((unsigned long)phi << 32) | (unsigned long)plo);
}

// ---------------------------------------------------------------------------
// Kernel 0: wsum[r] = sum_d W[r][d], f32, 32 blocks x 4 rows (wave per row).
// (einsum 'ed,ef->e' factorizes: bilinear[e] = (z_src.wsum)*(sum z_dst))
// ---------------------------------------------------------------------------
__global__ __launch_bounds__(256) void wsum_kernel(const float* __restrict__ W,
                                                   float* __restrict__ wsum)
{
    const int wv = threadIdx.x >> 6, lane = threadIdx.x & 63;
    const int r = blockIdx.x * 4 + wv;            // 0..127
    float2 v = *(const float2*)(W + (size_t)r * DIM + lane * 2);
    float s = v.x + v.y;
    s += __shfl_xor(s, 1);  s += __shfl_xor(s, 2);  s += __shfl_xor(s, 4);
    s += __shfl_xor(s, 8);  s += __shfl_xor(s, 16); s += __shfl_xor(s, 32);
    if (lane == 0) wsum[r] = s;
}

// ---------------------------------------------------------------------------
// Kernel 1 prep: blocks [0,nNodeBlk): half-wave per node —
//   zb8[n][:] = fp8(z[n][:]), s1[n] = z.wsum (f32), s2[n] = sum z (f32)
// blocks [nNodeBlk, +48): w1T8[h][k] = fp8(w1[k][h])  (384x32 transpose)
// ---------------------------------------------------------------------------
__global__ __launch_bounds__(256) void prep_kernel(
    const float* __restrict__ z, const float* __restrict__ w1,
    const float* __restrict__ wsum,
    unsigned char* __restrict__ zb8, unsigned char* __restrict__ w1T8,
    float* __restrict__ s1, float* __restrict__ s2,
    int nNodes, int nNodeBlk)
{
    const int b = blockIdx.x;
    const int tid = threadIdx.x;
    if (b < nNodeBlk) {
        const int n = b * 8 + (tid >> 5);
        const int l32 = tid & 31;
        if (n >= nNodes) return;                   // half-wave-uniform exit

        float4 v = *(const float4*)(z + (size_t)n * DIM + l32 * 4);
        float4 w = *(const float4*)(wsum + l32 * 4);

        float a1 = v.x * w.x + v.y * w.y + v.z * w.z + v.w * w.w;
        float a2 = v.x + v.y + v.z + v.w;

        *(unsigned*)(zb8 + (size_t)n * DIM + l32 * 4) = pk4_fp8(v.x, v.y, v.z, v.w);

        a1 += __shfl_xor(a1, 1);  a1 += __shfl_xor(a1, 2);  a1 += __shfl_xor(a1, 4);
        a1 += __shfl_xor(a1, 8);  a1 += __shfl_xor(a1, 16);
        a2 += __shfl_xor(a2, 1);  a2 += __shfl_xor(a2, 2);  a2 += __shfl_xor(a2, 4);
        a2 += __shfl_xor(a2, 8);  a2 += __shfl_xor(a2, 16);
        if (l32 == 0) { s1[n] = a1; s2[n] = a2; }
    } else {
        const int idx = (b - nNodeBlk) * 256 + tid;    // 0..12287 exact (48 blocks)
        const int k = idx >> 5, h = idx & 31;
        unsigned r = __builtin_amdgcn_cvt_pk_fp8_f32(w1[idx], 0.f, 0u, false);
        w1T8[(size_t)h * KTOT + k] = (unsigned char)(r & 0xff);
    }
}

// ---------------------------------------------------------------------------
// Kernel 2: edge kernel — wave-autonomous, zero LDS/barriers, fp8 gathers.
// fp8 row = 128B = 1 aligned L2 line; bilinear in f32 via L2-resident s1/s2.
// Grid sized to 8 blocks/CU = 32 waves/CU (VGPR=60 -> 8 waves/EU HW cap):
// R7's grid=1024 self-capped occupancy at 16 waves/CU while latency-bound.
// ---------------------------------------------------------------------------
__global__ __launch_bounds__(256, 2) void edge_kernel(
    const unsigned char* __restrict__ zb8, const int* __restrict__ ei,
    const float* __restrict__ s1, const float* __restrict__ s2,
    const unsigned char* __restrict__ w1T8, const float* __restrict__ b1,
    const float* __restrict__ w2, const float* __restrict__ b2,
    const float* __restrict__ bias, float* __restrict__ out,
    int nE, int nTiles)
{
    const int lane = threadIdx.x & 63;
    const int wv   = threadIdx.x >> 6;
    const int l15  = lane & 15;
    const int quad = lane >> 4;

    int t = blockIdx.x * 4 + wv;
    const int nW = gridDim.x * 4;
    if (t >= nTiles) return;

    // B fragments: B[k][n], n=l15 (h), k=quad*8+j per 32-step. 24 longs = 48 VGPR.
    long B0[12], B1[12];
    {
        const unsigned char* b0p = w1T8 + (size_t)l15 * KTOT + quad * 8;
        const unsigned char* b1p = w1T8 + (size_t)(16 + l15) * KTOT + quad * 8;
#pragma unroll
        for (int s = 0; s < 12; s++) {
            B0[s] = *(const long*)(b0p + s * 32);
            B1[s] = *(const long*)(b1p + s * 32);
        }
    }
    const float b1a = b1[l15],      w2a = w2[l15];
    const float b1b = b1[16 + l15], w2b = w2[16 + l15];
    const float cbias = bias[0] + b2[0];

    for (; t < nTiles; t += nW) {
        const int e = t * TPW + l15;
        int s_ = 0, d_ = 0;
        if (e < nE) { s_ = ei[e]; d_ = ei[nE + e]; }
        const float bil = s1[s_] * s2[d_];         // f32 path, lane l15 = edge l15

        const unsigned char* zsp = zb8 + (size_t)s_ * DIM + quad * 8;
        const unsigned char* zdp = zb8 + (size_t)d_ * DIM + quad * 8;
        long zs[4], zd[4];
#pragma unroll
        for (int k = 0; k < 4; k++) {
            zs[k] = *(const long*)(zsp + k * 32);
            zd[k] = *(const long*)(zdp + k * 32);
        }

        f32x4 acc0 = {0.f, 0.f, 0.f, 0.f};
        f32x4 acc1 = {0.f, 0.f, 0.f, 0.f};
#pragma unroll
        for (int k = 0; k < 4; k++) {              // zs block (K 0..127)
            acc0 = __builtin_amdgcn_mfma_f32_16x16x32_fp8_fp8(zs[k], B0[k], acc0, 0, 0, 0);
            acc1 = __builtin_amdgcn_mfma_f32_16x16x32_fp8_fp8(zs[k], B1[k], acc1, 0, 0, 0);
        }
#pragma unroll
        for (int k = 0; k < 4; k++) {              // zd block (K 128..255)
            acc0 = __builtin_amdgcn_mfma_f32_16x16x32_fp8_fp8(zd[k], B0[4 + k], acc0, 0, 0, 0);
            acc1 = __builtin_amdgcn_mfma_f32_16x16x32_fp8_fp8(zd[k], B1[4 + k], acc1, 0, 0, 0);
        }
#pragma unroll
        for (int k = 0; k < 4; k++) {              // product block (K 256..383)
            long p = prod_fp8(zs[k], zd[k]);
            acc0 = __builtin_amdgcn_mfma_f32_16x16x32_fp8_fp8(p, B0[8 + k], acc0, 0, 0, 0);
            acc1 = __builtin_amdgcn_mfma_f32_16x16x32_fp8_fp8(p, B1[8 + k], acc1, 0, 0, 0);
        }

        // epilogue (validated R3/R5): C/D col=l15 (h), row=quad*4+r (edge)
        const int e0 = t * TPW;
#pragma unroll
        for (int r = 0; r < 4; r++) {
            float v = fmaxf(acc0[r] + b1a, 0.f) * w2a
                    + fmaxf(acc1[r] + b1b, 0.f) * w2b;
            v += __shfl_xor(v, 1); v += __shfl_xor(v, 2);
            v += __shfl_xor(v, 4); v += __shfl_xor(v, 8);
            const int eL = quad * 4 + r;
            const float bilr = __shfl(bil, eL);    // bil replicated across quads
            if (l15 == r && (e0 + eL) < nE)
                out[e0 + eL] = v + bilr + cbias;
        }
    }
}

// ---------------------------------------------------------------------------
// Workspace: zb8 uchar[nNodes*128] | s1 f32[nNodes] | s2 f32[nNodes]
//          | wsum f32[128] | w1T8 uchar[32*384]        (~13.7 MB)
// ---------------------------------------------------------------------------
extern "C" void kernel_launch(void* const* d_in, const int* in_sizes, int n_in,
                              void* d_out, int out_size, void* d_ws, size_t ws_size,
                              hipStream_t stream)
{
    const float* z    = (const float*)d_in[0];
    const int*   ei   = (const int*)d_in[1];
    const float* W    = (const float*)d_in[2];
    const float* bias = (const float*)d_in[3];
    const float* w1   = (const float*)d_in[4];
    const float* b1   = (const float*)d_in[5];
    const float* w2   = (const float*)d_in[6];
    const float* b2   = (const float*)d_in[7];
    float* out = (float*)d_out;

    const int nNodes = in_sizes[0] / DIM;
    const int nE = out_size;

    unsigned char* zb8 = (unsigned char*)d_ws;
    float* s1   = (float*)(zb8 + (size_t)nNodes * DIM);
    float* s2   = s1 + nNodes;
    float* wsum = s2 + nNodes;
    unsigned char* w1T8 = (unsigned char*)(wsum + DIM);

    wsum_kernel<<<32, 256, 0, stream>>>(W, wsum);

    const int nNodeBlk = (nNodes + 7) / 8;
    prep_kernel<<<nNodeBlk + 48, 256, 0, stream>>>(z, w1, wsum, zb8, w1T8,
                                                   s1, s2, nNodes, nNodeBlk);

    const int nTiles = (nE + TPW - 1) / TPW;
    int grid = 2048;                     // 8 blocks/CU = 32 waves/CU (fills 8/EU cap)
    if (grid * 4 > nTiles) grid = (nTiles + 3) / 4;
    edge_kernel<<<grid, 256, 0, stream>>>(zb8, ei, s1, s2, w1T8,
                                          b1, w2, b2, bias, out, nE, nTiles);
}

// Round 9
// 128.109 us; speedup vs baseline: 1.2121x; 1.2121x over previous
//
#include <hip/hip_runtime.h>

#define DIM  128
#define HID  32
#define KTOT 384          // 3*DIM
#define TPW  16           // edges per wave-tile

typedef __attribute__((ext_vector_type(4))) float f32x4;
typedef __attribute__((ext_vector_type(2))) float f32x2;
typedef __attribute__((ext_vector_type(8))) int   i32x8;

// fp8 e4m3 (OCP on gfx950) pack via HW converts
static __device__ __forceinline__ unsigned pk4_fp8(float a, float b, float c, float d) {
    unsigned r = __builtin_amdgcn_cvt_pk_fp8_f32(a, b, 0u, false);
    return __builtin_amdgcn_cvt_pk_fp8_f32(c, d, r, true);
}

// elementwise product of two 32-byte fp8 vectors (8 dwords), result fp8
static __device__ __forceinline__ i32x8 prod_fp8x32(i32x8 a, i32x8 b) {
    i32x8 r;
#pragma unroll
    for (int j = 0; j < 8; j++) {
        unsigned av = (unsigned)a[j], bv = (unsigned)b[j];
        f32x2 a0 = __builtin_amdgcn_cvt_pk_f32_fp8(av, false);
        f32x2 a1 = __builtin_amdgcn_cvt_pk_f32_fp8(av, true);
        f32x2 b0 = __builtin_amdgcn_cvt_pk_f32_fp8(bv, false);
        f32x2 b1 = __builtin_amdgcn_cvt_pk_f32_fp8(bv, true);
        f32x2 p0 = a0 * b0, p1 = a1 * b1;
        unsigned pr = __builtin_amdgcn_cvt_pk_fp8_f32(p0.x, p0.y, 0u, false);
        pr = __builtin_amdgcn_cvt_pk_fp8_f32(p1.x, p1.y, pr, true);
        r[j] = (int)pr;
    }
    return r;
}

// 32-byte (8-dword) load as two dwordx4
static __device__ __forceinline__ i32x8 ld32(const unsigned char* p) {
    int4 lo = *(const int4*)p;
    int4 hi = *(const int4*)(p + 16);
    i32x8 v;
    v[0] = lo.x; v[1] = lo.y; v[2] = lo.z; v[3] = lo.w;
    v[4] = hi.x; v[5] = hi.y; v[6] = hi.z; v[7] = hi.w;
    return v;
}

// ---------------------------------------------------------------------------
// Kernel 0: wsum[r] = sum_d W[r][d], f32, 32 blocks x 4 rows (wave per row).
// (einsum 'ed,ef->e' factorizes: bilinear[e] = (z_src.wsum)*(sum z_dst))
// ---------------------------------------------------------------------------
__global__ __launch_bounds__(256) void wsum_kernel(const float* __restrict__ W,
                                                   float* __restrict__ wsum)
{
    const int wv = threadIdx.x >> 6, lane = threadIdx.x & 63;
    const int r = blockIdx.x * 4 + wv;            // 0..127
    float2 v = *(const float2*)(W + (size_t)r * DIM + lane * 2);
    float s = v.x + v.y;
    s += __shfl_xor(s, 1);  s += __shfl_xor(s, 2);  s += __shfl_xor(s, 4);
    s += __shfl_xor(s, 8);  s += __shfl_xor(s, 16); s += __shfl_xor(s, 32);
    if (lane == 0) wsum[r] = s;
}

// ---------------------------------------------------------------------------
// Kernel 1 prep: blocks [0,nNodeBlk): half-wave per node —
//   zb8[n][:] = fp8(z[n][:]), s1[n] = z.wsum (f32), s2[n] = sum z (f32)
// blocks [nNodeBlk, +48): w1T8[h][k] = fp8(w1[k][h])  (384x32 transpose)
// ---------------------------------------------------------------------------
__global__ __launch_bounds__(256) void prep_kernel(
    const float* __restrict__ z, const float* __restrict__ w1,
    const float* __restrict__ wsum,
    unsigned char* __restrict__ zb8, unsigned char* __restrict__ w1T8,
    float* __restrict__ s1, float* __restrict__ s2,
    int nNodes, int nNodeBlk)
{
    const int b = blockIdx.x;
    const int tid = threadIdx.x;
    if (b < nNodeBlk) {
        const int n = b * 8 + (tid >> 5);
        const int l32 = tid & 31;
        if (n >= nNodes) return;                   // half-wave-uniform exit

        float4 v = *(const float4*)(z + (size_t)n * DIM + l32 * 4);
        float4 w = *(const float4*)(wsum + l32 * 4);

        float a1 = v.x * w.x + v.y * w.y + v.z * w.z + v.w * w.w;
        float a2 = v.x + v.y + v.z + v.w;

        *(unsigned*)(zb8 + (size_t)n * DIM + l32 * 4) = pk4_fp8(v.x, v.y, v.z, v.w);

        a1 += __shfl_xor(a1, 1);  a1 += __shfl_xor(a1, 2);  a1 += __shfl_xor(a1, 4);
        a1 += __shfl_xor(a1, 8);  a1 += __shfl_xor(a1, 16);
        a2 += __shfl_xor(a2, 1);  a2 += __shfl_xor(a2, 2);  a2 += __shfl_xor(a2, 4);
        a2 += __shfl_xor(a2, 8);  a2 += __shfl_xor(a2, 16);
        if (l32 == 0) { s1[n] = a1; s2[n] = a2; }
    } else {
        const int idx = (b - nNodeBlk) * 256 + tid;    // 0..12287 exact (48 blocks)
        const int k = idx >> 5, h = idx & 31;
        unsigned r = __builtin_amdgcn_cvt_pk_fp8_f32(w1[idx], 0.f, 0u, false);
        w1T8[(size_t)h * KTOT + k] = (unsigned char)(r & 0xff);
    }
}

// ---------------------------------------------------------------------------
// Kernel 2: edge kernel — wave-autonomous, zero LDS/barriers, fp8 gathers,
// K=128 MFMA (mfma_scale_f32_16x16x128_f8f6f4, unit e8m0 scales = fp8 matmul).
// A-frag = 32 contiguous B/lane -> each 128B row fetched by 2 dwordx4 instrs
// (R7 needed 4 dwordx2: 4 separate line-touches per row -> request-rate wall).
// A and B use the same assumed lane->k mapping so the contraction is
// permutation-safe; C/D layout is shape-determined = validated 16x16 epilogue.
// Bilinear in f32 via L2-resident s1/s2. Grid 1024 (R8's 2048 regressed).
// ---------------------------------------------------------------------------
__global__ __launch_bounds__(256, 2) void edge_kernel(
    const unsigned char* __restrict__ zb8, const int* __restrict__ ei,
    const float* __restrict__ s1, const float* __restrict__ s2,
    const unsigned char* __restrict__ w1T8, const float* __restrict__ b1,
    const float* __restrict__ w2, const float* __restrict__ b2,
    const float* __restrict__ bias, float* __restrict__ out,
    int nE, int nTiles)
{
    const int lane = threadIdx.x & 63;
    const int wv   = threadIdx.x >> 6;
    const int l15  = lane & 15;
    const int quad = lane >> 4;
    const int sOne = 0x7F7F7F7F;                  // e8m0 1.0 in every byte

    int t = blockIdx.x * 4 + wv;
    const int nW = gridDim.x * 4;
    if (t >= nTiles) return;

    // B fragments: chunk c covers k=[c*128,(c+1)*128); lane (l15=h-col, quad)
    // holds 32 contiguous k at quad*32. 6 x i32x8 = 48 VGPRs.
    i32x8 B0[3], B1[3];
    {
        const unsigned char* b0p = w1T8 + (size_t)l15 * KTOT + quad * 32;
        const unsigned char* b1p = w1T8 + (size_t)(16 + l15) * KTOT + quad * 32;
#pragma unroll
        for (int c = 0; c < 3; c++) {
            B0[c] = ld32(b0p + c * 128);
            B1[c] = ld32(b1p + c * 128);
        }
    }
    const float b1a = b1[l15],      w2a = w2[l15];
    const float b1b = b1[16 + l15], w2b = w2[16 + l15];
    const float cbias = bias[0] + b2[0];

    for (; t < nTiles; t += nW) {
        const int e = t * TPW + l15;
        int s_ = 0, d_ = 0;
        if (e < nE) { s_ = ei[e]; d_ = ei[nE + e]; }
        const float bil = s1[s_] * s2[d_];         // f32 path, lane l15 = edge l15

        // rows: lane (l15=edge, quad) loads 32B at quad*32 -> 2 dwordx4 each
        i32x8 zs8 = ld32(zb8 + (size_t)s_ * DIM + quad * 32);
        i32x8 zd8 = ld32(zb8 + (size_t)d_ * DIM + quad * 32);

        f32x4 acc0 = {0.f, 0.f, 0.f, 0.f};
        f32x4 acc1 = {0.f, 0.f, 0.f, 0.f};
        // chunk 0: zs (K 0..127)
        acc0 = __builtin_amdgcn_mfma_scale_f32_16x16x128_f8f6f4(
                   zs8, B0[0], acc0, 0, 0, 0, sOne, 0, sOne);
        acc1 = __builtin_amdgcn_mfma_scale_f32_16x16x128_f8f6f4(
                   zs8, B1[0], acc1, 0, 0, 0, sOne, 0, sOne);
        // chunk 1: zd (K 128..255)
        acc0 = __builtin_amdgcn_mfma_scale_f32_16x16x128_f8f6f4(
                   zd8, B0[1], acc0, 0, 0, 0, sOne, 0, sOne);
        acc1 = __builtin_amdgcn_mfma_scale_f32_16x16x128_f8f6f4(
                   zd8, B1[1], acc1, 0, 0, 0, sOne, 0, sOne);
        // chunk 2: zs*zd (K 256..383)
        i32x8 p8 = prod_fp8x32(zs8, zd8);
        acc0 = __builtin_amdgcn_mfma_scale_f32_16x16x128_f8f6f4(
                   p8, B0[2], acc0, 0, 0, 0, sOne, 0, sOne);
        acc1 = __builtin_amdgcn_mfma_scale_f32_16x16x128_f8f6f4(
                   p8, B1[2], acc1, 0, 0, 0, sOne, 0, sOne);

        // epilogue (validated R3..R8): C/D col=l15 (h), row=quad*4+r (edge)
        const int e0 = t * TPW;
#pragma unroll
        for (int r = 0; r < 4; r++) {
            float v = fmaxf(acc0[r] + b1a, 0.f) * w2a
                    + fmaxf(acc1[r] + b1b, 0.f) * w2b;
            v += __shfl_xor(v, 1); v += __shfl_xor(v, 2);
            v += __shfl_xor(v, 4); v += __shfl_xor(v, 8);
            const int eL = quad * 4 + r;
            const float bilr = __shfl(bil, eL);    // bil replicated across quads
            if (l15 == r && (e0 + eL) < nE)
                out[e0 + eL] = v + bilr + cbias;
        }
    }
}

// ---------------------------------------------------------------------------
// Workspace: zb8 uchar[nNodes*128] | s1 f32[nNodes] | s2 f32[nNodes]
//          | wsum f32[128] | w1T8 uchar[32*384]        (~13.7 MB)
// ---------------------------------------------------------------------------
extern "C" void kernel_launch(void* const* d_in, const int* in_sizes, int n_in,
                              void* d_out, int out_size, void* d_ws, size_t ws_size,
                              hipStream_t stream)
{
    const float* z    = (const float*)d_in[0];
    const int*   ei   = (const int*)d_in[1];
    const float* W    = (const float*)d_in[2];
    const float* bias = (const float*)d_in[3];
    const float* w1   = (const float*)d_in[4];
    const float* b1   = (const float*)d_in[5];
    const float* w2   = (const float*)d_in[6];
    const float* b2   = (const float*)d_in[7];
    float* out = (float*)d_out;

    const int nNodes = in_sizes[0] / DIM;
    const int nE = out_size;

    unsigned char* zb8 = (unsigned char*)d_ws;
    float* s1   = (float*)(zb8 + (size_t)nNodes * DIM);
    float* s2   = s1 + nNodes;
    float* wsum = s2 + nNodes;
    unsigned char* w1T8 = (unsigned char*)(wsum + DIM);

    wsum_kernel<<<32, 256, 0, stream>>>(W, wsum);

    const int nNodeBlk = (nNodes + 7) / 8;
    prep_kernel<<<nNodeBlk + 48, 256, 0, stream>>>(z, w1, wsum, zb8, w1T8,
                                                   s1, s2, nNodes, nNodeBlk);

    const int nTiles = (nE + TPW - 1) / TPW;
    int grid = 1024;                     // R8: 2048 regressed (tail + init amortization)
    if (grid * 4 > nTiles) grid = (nTiles + 3) / 4;
    edge_kernel<<<grid, 256, 0, stream>>>(zb8, ei, s1, s2, w1T8,
                                          b1, w2, b2, bias, out, nE, nTiles);
}